// Round 4
// baseline (860.416 us; speedup 1.0000x reference)
//
#include <hip/hip_runtime.h>

#define DIN 100
#define DD  64
#define NE  250000
#define NB  16
#define NN  50000
#define NR  500
#define NM  500000
#define NH  (NM + NN)

// workspace layout (float offsets). H doubles as TA (rows<nmax, in-place)
// and HU2 (rows >= NM, in-place).
#define H_OFF    64
#define TA2_OFF  (H_OFF + NH*DD)
#define RT_OFF   (TA2_OFF + NE*DD)
#define QT_OFF   (RT_OFF + 4*NR*DD)
#define LG_OFF   (QT_OFF + 4*NB*DD)

// k_tf grid segmentation: pool0 (2 passes) : pool1 : pool2 ~ 430:215:50
#define PA 475
#define PB 238
#define PC 55

__device__ __forceinline__ void fma4x4(const float4 x, const float4 w, float4 acc[4]) {
  acc[0].x += x.x*w.x; acc[0].y += x.x*w.y; acc[0].z += x.x*w.z; acc[0].w += x.x*w.w;
  acc[1].x += x.y*w.x; acc[1].y += x.y*w.y; acc[1].z += x.y*w.z; acc[1].w += x.y*w.w;
  acc[2].x += x.z*w.x; acc[2].y += x.z*w.y; acc[2].z += x.z*w.z; acc[2].w += x.z*w.w;
  acc[3].x += x.w*w.x; acc[3].y += x.w*w.y; acc[3].z += x.w*w.z; acc[3].w += x.w*w.w;
}

__device__ __forceinline__ float fc(const float4& v, int i) {
  return ((const float*)&v)[i];
}

__device__ __forceinline__ float4 leaky4(float4 v) {
  v.x = v.x > 0.f ? v.x : 0.2f*v.x;
  v.y = v.y > 0.f ? v.y : 0.2f*v.y;
  v.z = v.z > 0.f ? v.z : 0.2f*v.z;
  v.w = v.w > 0.f ? v.w : 0.2f*v.w;
  return v;
}

__global__ void k_init(int* wsI, float* bsum) {
  if (threadIdx.x == 0) { wsI[0] = 0x7fffffff; wsI[1] = 0; }
  if (threadIdx.x < NB) bsum[threadIdx.x] = 0.f;
}

__global__ void k_limits(const int* __restrict__ edges, int* __restrict__ wsI) {
  int i = blockIdx.x * blockDim.x + threadIdx.x;
  int mn = 0x7fffffff, mx = -1;
  if (i < NE) { int v = edges[i*8 + 7]; mn = v; mx = v; }
  for (int off = 32; off > 0; off >>= 1) {
    mn = min(mn, __shfl_down(mn, off));
    mx = max(mx, __shfl_down(mx, off));
  }
  if ((threadIdx.x & 63) == 0) {
    atomicMin(&wsI[0], mn);
    atomicMax(&wsI[1], mx + 1);
  }
}

// one 64-thread block per (rel row | batch row): builds per-rel / per-batch tables
__global__ void k_tables(const float* __restrict__ rtab,
                         const float* __restrict__ qh, const float* __restrict__ qr,
                         const float* __restrict__ pW, const float* __restrict__ pb,
                         const float* __restrict__ g1_lW, const float* __restrict__ g1_lb,
                         const float* __restrict__ g1_rW, const float* __restrict__ g1_rb,
                         const float* __restrict__ g2_lW, const float* __restrict__ g2_lb,
                         const float* __restrict__ g2_rW, const float* __restrict__ g2_rb,
                         float* __restrict__ rT, float* __restrict__ qT) {
  __shared__ float xs[DIN], xs2[DIN], ps[DD], ps2[DD];
  const int d = threadIdx.x;
  const int blk = blockIdx.x;
  if (blk < NR) {
    for (int k = d; k < DIN; k += 64) xs[k] = rtab[blk*DIN + k];
    __syncthreads();
    float a = pb[d];
    for (int k = 0; k < DIN; ++k) a += xs[k] * pW[k*DD + d];
    ps[d] = tanhf(a);
    __syncthreads();
    float o1 = 0.f, o2 = 0.f, o3 = 0.f, o4 = 0.f;
    for (int k = 0; k < DD; ++k) {
      float p = ps[k];
      o1 += p * g1_lW[(DD + k)*DD + d];
      o2 += p * g1_rW[(DD + k)*DD + d];
      o3 += p * g2_lW[(DD + k)*DD + d];
      o4 += p * g2_rW[(DD + k)*DD + d];
    }
    rT[(0*NR + blk)*DD + d] = o1;
    rT[(1*NR + blk)*DD + d] = o2;
    rT[(2*NR + blk)*DD + d] = o3;
    rT[(3*NR + blk)*DD + d] = o4;
  } else {
    const int b = blk - NR;
    for (int k = d; k < DIN; k += 64) { xs[k] = qh[b*DIN + k]; xs2[k] = qr[b*DIN + k]; }
    __syncthreads();
    float a = pb[d], a2 = pb[d];
    for (int k = 0; k < DIN; ++k) { a += xs[k]*pW[k*DD + d]; a2 += xs2[k]*pW[k*DD + d]; }
    ps[d] = tanhf(a); ps2[d] = tanhf(a2);
    __syncthreads();
    float o1 = g1_lb[d], o2 = g1_rb[d], o3 = g2_lb[d], o4 = g2_rb[d];
    for (int k = 0; k < DD; ++k) {
      float p = ps[k], p2 = ps2[k];
      o1 += p * g1_lW[(2*DD + k)*DD + d] + p2 * g1_lW[(3*DD + k)*DD + d];
      o2 += p * g1_rW[(2*DD + k)*DD + d] + p2 * g1_rW[(3*DD + k)*DD + d];
      o3 += p * g2_lW[(2*DD + k)*DD + d] + p2 * g2_lW[(3*DD + k)*DD + d];
      o4 += p * g2_rW[(2*DD + k)*DD + d] + p2 * g2_rW[(3*DD + k)*DD + d];
    }
    qT[(0*NB + b)*DD + d] = o1;
    qT[(1*NB + b)*DD + d] = o2;
    qT[(2*NB + b)*DD + d] = o3;
    qT[(3*NB + b)*DD + d] = o4;
  }
}

// persistent proj: H = tanh(X@pW+pb), 256-row tiles, 8x8 register tile.
// X rows read straight from global (8 lanes share each address -> coalescer
// broadcast, ~1x traffic). Only pW in LDS -> 3 blocks/CU, no k-loop barriers.
__global__ __launch_bounds__(256, 3)
void k_proj(const float* __restrict__ hcon, const float* __restrict__ huncon,
            const float* __restrict__ pW, const float* __restrict__ pb,
            const int* __restrict__ lim, float* __restrict__ H) {
  __shared__ __align__(16) float pWs[DIN*DD];        // 25.6 KB
  const int tid = threadIdx.x;
  for (int i = tid; i < DIN*DD; i += 256) pWs[i] = pW[i];
  const int tc = tid & 7, tr = tid >> 3;
  const int c0 = tc << 3;
  const float4 pb0 = *(const float4*)&pb[c0];
  const float4 pb1 = *(const float4*)&pb[c0 + 4];
  const int nmax = lim[1];
  const int t_lo = (nmax + 255) >> 8;
  const int NT   = t_lo + ((NN + 255) >> 8);
  __syncthreads();
  for (int t = blockIdx.x; t < NT; t += gridDim.x) {
    const bool lo = (t < t_lo);
    const int row0 = lo ? (t << 8) : (NM + ((t - t_lo) << 8));
    const int rlim = lo ? nmax : NH;
    const float* srcs[8];
    #pragma unroll
    for (int r = 0; r < 8; ++r) {
      int row = row0 + tr*8 + r;
      if (row >= rlim) row = rlim - 1;
      srcs[r] = lo ? &hcon[(size_t)row*DIN] : &huncon[(size_t)(row - NM)*DIN];
    }
    float4 acc[2][2][4];
    #pragma unroll
    for (int a = 0; a < 2; ++a)
      #pragma unroll
      for (int b = 0; b < 2; ++b)
        #pragma unroll
        for (int i = 0; i < 4; ++i) acc[a][b][i] = make_float4(0.f,0.f,0.f,0.f);
    for (int kb = 0; kb < DIN; kb += 4) {
      float4 xv[8];
      #pragma unroll
      for (int r = 0; r < 8; ++r) xv[r] = *(const float4*)(srcs[r] + kb);
      #pragma unroll
      for (int kk = 0; kk < 4; ++kk) {
        float4 w0 = *(const float4*)&pWs[(kb + kk)*DD + c0];
        float4 w1 = *(const float4*)&pWs[(kb + kk)*DD + c0 + 4];
        float4 xa = make_float4(fc(xv[0],kk), fc(xv[1],kk), fc(xv[2],kk), fc(xv[3],kk));
        float4 xb = make_float4(fc(xv[4],kk), fc(xv[5],kk), fc(xv[6],kk), fc(xv[7],kk));
        fma4x4(xa, w0, acc[0][0]); fma4x4(xa, w1, acc[0][1]);
        fma4x4(xb, w0, acc[1][0]); fma4x4(xb, w1, acc[1][1]);
      }
    }
    #pragma unroll
    for (int a = 0; a < 2; ++a)
      #pragma unroll
      for (int i = 0; i < 4; ++i) {
        int row = row0 + tr*8 + a*4 + i;
        if (row < rlim) {
          float4 o0, o1;
          o0.x = tanhf(acc[a][0][i].x + pb0.x);
          o0.y = tanhf(acc[a][0][i].y + pb0.y);
          o0.z = tanhf(acc[a][0][i].z + pb0.z);
          o0.w = tanhf(acc[a][0][i].w + pb0.w);
          o1.x = tanhf(acc[a][1][i].x + pb1.x);
          o1.y = tanhf(acc[a][1][i].y + pb1.y);
          o1.z = tanhf(acc[a][1][i].z + pb1.z);
          o1.w = tanhf(acc[a][1][i].w + pb1.w);
          *(float4*)&H[(size_t)row*DD + c0]     = o0;
          *(float4*)&H[(size_t)row*DD + c0 + 4] = o1;
        }
      }
  }
}

// 64x64 GEMM over 8 broadcast-loaded rows: acc[2][2][4] = rows(tr*8..+7) x cols(c0..+7)
__device__ __forceinline__ void gemm64(const float* const* srcs, const float* __restrict__ Wss,
                                       int c0, float4 acc[2][2][4]) {
  #pragma unroll
  for (int a = 0; a < 2; ++a)
    #pragma unroll
    for (int b = 0; b < 2; ++b)
      #pragma unroll
      for (int i = 0; i < 4; ++i) acc[a][b][i] = make_float4(0.f,0.f,0.f,0.f);
  for (int kb = 0; kb < DD; kb += 4) {
    float4 xv[8];
    #pragma unroll
    for (int r = 0; r < 8; ++r) xv[r] = *(const float4*)(srcs[r] + kb);
    #pragma unroll
    for (int kk = 0; kk < 4; ++kk) {
      float4 w0 = *(const float4*)&Wss[(kb + kk)*DD + c0];
      float4 w1 = *(const float4*)&Wss[(kb + kk)*DD + c0 + 4];
      float4 xa = make_float4(fc(xv[0],kk), fc(xv[1],kk), fc(xv[2],kk), fc(xv[3],kk));
      float4 xb = make_float4(fc(xv[4],kk), fc(xv[5],kk), fc(xv[6],kk), fc(xv[7],kk));
      fma4x4(xa, w0, acc[0][0]); fma4x4(xa, w1, acc[0][1]);
      fma4x4(xb, w0, acc[1][0]); fma4x4(xb, w1, acc[1][1]);
    }
  }
}

// persistent transform, H rows broadcast-loaded from global, weights-only LDS.
// pool 0: rows<nvi : TA2=H@g2_lW (pass1), TA=H@g1_lW in place (pass2)
// pool 1: rows in [nvi,nmax): TA=H@g1_rW in place
// pool 2: huncon rows: HU2=H@g2_rW in place
// In-place safety: one __syncthreads between last H read and H overwrite;
// tiles are block-private; boundary-tile cross-pool reads are discarded.
__global__ __launch_bounds__(256, 3)
void k_tf(const float* __restrict__ g1_lW, const float* __restrict__ g1_rW,
          const float* __restrict__ g2_lW, const float* __restrict__ g2_rW,
          const int* __restrict__ lim,
          float* __restrict__ H, float* __restrict__ TA2) {
  __shared__ __align__(16) float Ws0[DD*DD];   // 16 KB
  __shared__ __align__(16) float Ws1[DD*DD];   // 16 KB
  const int tid = threadIdx.x;
  const int nvi  = lim[0];
  const int nmax = lim[1];
  int pool, pbase, pgrid;
  if (blockIdx.x < PA)           { pool = 0; pbase = blockIdx.x;           pgrid = PA; }
  else if (blockIdx.x < PA + PB) { pool = 1; pbase = blockIdx.x - PA;      pgrid = PB; }
  else                           { pool = 2; pbase = blockIdx.x - PA - PB; pgrid = PC; }
  if (pool == 0) {
    for (int i = tid; i < DD*DD; i += 256) { Ws0[i] = g1_lW[i]; Ws1[i] = g2_lW[i]; }
  } else if (pool == 1) {
    for (int i = tid; i < DD*DD; i += 256) Ws0[i] = g1_rW[i];
  } else {
    for (int i = tid; i < DD*DD; i += 256) Ws0[i] = g2_rW[i];
  }
  int t_begin, t_count, row_base, rlim, wlo, whi;
  if (pool == 0)      { t_begin = 0;        t_count = (nvi + 255) >> 8;                 row_base = 0;  rlim = nmax; wlo = 0;   whi = nvi;  }
  else if (pool == 1) { t_begin = nvi >> 8; t_count = ((nmax + 255) >> 8) - (nvi >> 8); row_base = 0;  rlim = nmax; wlo = nvi; whi = nmax; }
  else                { t_begin = 0;        t_count = (NN + 255) >> 8;                  row_base = NM; rlim = NH;   wlo = NM;  whi = NH;   }
  const int tc = tid & 7, tr = tid >> 3;
  const int c0 = tc << 3;
  __syncthreads();
  for (int tt = pbase; tt < t_count; tt += pgrid) {
    const int row0 = row_base + ((t_begin + tt) << 8);
    const float* srcs[8];
    #pragma unroll
    for (int r = 0; r < 8; ++r) {
      int row = row0 + tr*8 + r;
      if (row >= rlim) row = rlim - 1;
      srcs[r] = &H[(size_t)row*DD];
    }
    float4 acc[2][2][4];
    if (pool == 0) {           // pass 1: TA2 (separate buffer, no barrier needed)
      gemm64(srcs, Ws1, c0, acc);
      #pragma unroll
      for (int a = 0; a < 2; ++a)
        #pragma unroll
        for (int i = 0; i < 4; ++i) {
          int row = row0 + tr*8 + a*4 + i;
          if (row >= wlo && row < whi) {
            *(float4*)&TA2[(size_t)row*DD + c0]     = acc[a][0][i];
            *(float4*)&TA2[(size_t)row*DD + c0 + 4] = acc[a][1][i];
          }
        }
    }
    gemm64(srcs, Ws0, c0, acc);  // pass 2: in-place
    __syncthreads();             // drain all H reads before overwrite
    #pragma unroll
    for (int a = 0; a < 2; ++a)
      #pragma unroll
      for (int i = 0; i < 4; ++i) {
        int row = row0 + tr*8 + a*4 + i;
        if (row >= wlo && row < whi) {
          *(float4*)&H[(size_t)row*DD + c0]     = acc[a][0][i];
          *(float4*)&H[(size_t)row*DD + c0 + 4] = acc[a][1][i];
        }
      }
  }
}

// persistent edge kernel: cW1/cW2 transposed + cb resident in LDS.
// Dot partials reduced via wave-local __shfl_xor (edge-quad owned by 16
// consecutive lanes) instead of LDS atomics.
__global__ __launch_bounds__(256, 2)
void k_edges(const int* __restrict__ edges,
             const float* __restrict__ TA, const float* __restrict__ TA2,
             const float* __restrict__ HU2,
             const float* __restrict__ rT, const float* __restrict__ qT,
             const float* __restrict__ cW1, const float* __restrict__ cb1,
             const float* __restrict__ cW2, const float* __restrict__ cb2,
             float* __restrict__ logits) {
  __shared__ __align__(16) float Wt1s[DD*68];
  __shared__ __align__(16) float Wt2s[DD*68];
  __shared__ __align__(16) float Lt[DD][68];
  __shared__ __align__(16) float Rt[DD][68];
  __shared__ __align__(16) float4 cbs4[2][16];
  __shared__ float lg[64];
  __shared__ int   se[64*8];
  const int tid = threadIdx.x;
  for (int i = tid; i < DD*DD; i += 256) {
    int k = i >> 6, d = i & 63;
    Wt1s[d*68 + k] = cW1[i];   // Wt[d][k] = cW[k][d]
    Wt2s[d*68 + k] = cW2[i];
  }
  if (tid < 16) {
    cbs4[0][tid] = *(const float4*)&cb1[tid*4];
    cbs4[1][tid] = *(const float4*)&cb2[tid*4];
  }
  const int e   = tid >> 2;          // staging: 4 lanes per edge
  const int d0  = (tid & 3) * 16;
  const int eq0 = (tid >> 4) << 2;   // GEMM/dot: edge-quad (wave-local owners)
  const int jq0 = (tid & 15) << 2;   // j-quad
  __syncthreads();
  const int NT = (NE + 63) / 64;
  for (int tile = blockIdx.x; tile < NT; tile += gridDim.x) {
    const int e0 = tile * 64;
    const int ecnt = min(64, NE - e0);
    for (int i = tid; i < 64*8; i += 256) se[i] = (i < ecnt*8) ? edges[e0*8 + i] : 0;
    if (tid < 64) lg[tid] = 0.f;
    __syncthreads();
    const int rel = se[e*8 + 3];
    const int eg  = se[e*8 + 0];
    const int li  = se[e*8 + 6];
    for (int g = 0; g < 2; ++g) {
      const float* Lb = g ? TA2 : TA;
      const float* Rb = g ? HU2 : TA;
      const float* rL = rT + (g ? 2*NR*DD : 0);
      const float* rR = rT + (g ? 3*NR*DD : 1*NR*DD);
      const float* qL = qT + (g ? 2*NB*DD : 0);
      const float* qR = qT + (g ? 3*NB*DD : 1*NB*DD);
      const float* Wts = g ? Wt2s : Wt1s;
      const int ri = g ? se[e*8 + 2] : se[e*8 + 7];
      float cbp = 0.f;
      #pragma unroll
      for (int di = 0; di < 4; ++di) {
        const int d = d0 + 4*di;
        float4 l = *(const float4*)&Lb[(size_t)li*DD + d];
        float4 t = *(const float4*)&rL[rel*DD + d];
        float4 u = *(const float4*)&qL[eg*DD + d];
        l.x += t.x + u.x; l.y += t.y + u.y; l.z += t.z + u.z; l.w += t.w + u.w;
        l = leaky4(l);
        Lt[d+0][e] = l.x; Lt[d+1][e] = l.y; Lt[d+2][e] = l.z; Lt[d+3][e] = l.w;
        float4 c = cbs4[g][d >> 2];
        cbp += l.x*c.x + l.y*c.y + l.z*c.z + l.w*c.w;
        float4 r = *(const float4*)&Rb[(size_t)ri*DD + d];
        t = *(const float4*)&rR[rel*DD + d];
        u = *(const float4*)&qR[eg*DD + d];
        r.x += t.x + u.x; r.y += t.y + u.y; r.z += t.z + u.z; r.w += t.w + u.w;
        r = leaky4(r);
        Rt[d+0][e] = r.x; Rt[d+1][e] = r.y; Rt[d+2][e] = r.z; Rt[d+3][e] = r.w;
      }
      atomicAdd(&lg[e], cbp);
      __syncthreads();
      float4 z[4] = {{0,0,0,0},{0,0,0,0},{0,0,0,0},{0,0,0,0}};
      for (int d = 0; d < DD; ++d) {
        float4 x = *(const float4*)&Lt[d][eq0];        // broadcast across 16 lanes
        float4 w = *(const float4*)&Wts[d*68 + jq0];
        fma4x4(x, w, z);  // z[edge in quad][j in quad]
      }
      float4 rv0 = *(const float4*)&Rt[jq0+0][eq0];
      float4 rv1 = *(const float4*)&Rt[jq0+1][eq0];
      float4 rv2 = *(const float4*)&Rt[jq0+2][eq0];
      float4 rv3 = *(const float4*)&Rt[jq0+3][eq0];
      float p0 = z[0].x*rv0.x + z[0].y*rv1.x + z[0].z*rv2.x + z[0].w*rv3.x;
      float p1 = z[1].x*rv0.y + z[1].y*rv1.y + z[1].z*rv2.y + z[1].w*rv3.y;
      float p2 = z[2].x*rv0.z + z[2].y*rv1.z + z[2].z*rv2.z + z[2].w*rv3.z;
      float p3 = z[3].x*rv0.w + z[3].y*rv1.w + z[3].z*rv2.w + z[3].w*rv3.w;
      #pragma unroll
      for (int m = 1; m < 16; m <<= 1) {
        p0 += __shfl_xor(p0, m);
        p1 += __shfl_xor(p1, m);
        p2 += __shfl_xor(p2, m);
        p3 += __shfl_xor(p3, m);
      }
      if ((tid & 15) == 0) {   // unique owner per edge; cbp atomics drained by barrier
        lg[eq0+0] += p0;
        lg[eq0+1] += p1;
        lg[eq0+2] += p2;
        lg[eq0+3] += p3;
      }
      __syncthreads();
    }
    if (tid < ecnt) logits[e0 + tid] = lg[tid];
    __syncthreads();
  }
}

__global__ void k_softmax(const int* __restrict__ edges, const float* __restrict__ logits,
                          const float* __restrict__ na, float* __restrict__ out) {
  int e = blockIdx.x * blockDim.x + threadIdx.x;
  if (e >= NE) return;
  int seg = edges[e*8 + 4];
  if (e > 0 && edges[(e-1)*8 + 4] == seg) return;  // not a segment head
  int j = e;
  float m = -1e30f;
  while (j < NE && edges[j*8 + 4] == seg) { m = fmaxf(m, logits[j]); ++j; }
  float s = 0.f;
  for (int t = e; t < j; ++t) s += expf(logits[t] - m);
  int eg = edges[e*8 + 0], vi = edges[e*8 + 1];
  float scale = na[eg*NN + vi] / s;
  for (int t = e; t < j; ++t) {
    int vj = edges[t*8 + 2];
    __hip_atomic_fetch_add(&out[eg*NN + vj], expf(logits[t] - m) * scale,
                           __ATOMIC_RELAXED, __HIP_MEMORY_SCOPE_AGENT);
  }
}

__global__ void k_rowsum(const float* __restrict__ out, float* __restrict__ bsum) {
  int b = blockIdx.y;
  float s = 0.f;
  for (int n = blockIdx.x * blockDim.x + threadIdx.x; n < NN; n += gridDim.x * blockDim.x)
    s += out[b*NN + n];
  for (int off = 32; off > 0; off >>= 1) s += __shfl_down(s, off);
  if ((threadIdx.x & 63) == 0)
    __hip_atomic_fetch_add(&bsum[b], s, __ATOMIC_RELAXED, __HIP_MEMORY_SCOPE_AGENT);
}

__global__ void k_div(float* __restrict__ out, const float* __restrict__ bsum) {
  int i = blockIdx.x * blockDim.x + threadIdx.x;
  if (i < NB*NN) out[i] /= bsum[i / NN];
}

extern "C" void kernel_launch(void* const* d_in, const int* in_sizes, int n_in,
                              void* d_out, int out_size, void* d_ws, size_t ws_size,
                              hipStream_t stream) {
  (void)in_sizes; (void)n_in; (void)out_size; (void)ws_size;
  const float* na     = (const float*)d_in[0];
  const int*   edges  = (const int*)  d_in[1];
  const float* huncon = (const float*)d_in[2];
  const float* hcon   = (const float*)d_in[3];
  const float* rtab   = (const float*)d_in[4];
  const float* qh     = (const float*)d_in[5];
  const float* qr     = (const float*)d_in[6];
  const float* pW     = (const float*)d_in[7];
  const float* pb     = (const float*)d_in[8];
  const float* g1_lW  = (const float*)d_in[9];
  const float* g1_lb  = (const float*)d_in[10];
  const float* g1_rW  = (const float*)d_in[11];
  const float* g1_rb  = (const float*)d_in[12];
  const float* g1_cW  = (const float*)d_in[13];
  const float* g1_cb  = (const float*)d_in[14];
  const float* g2_lW  = (const float*)d_in[15];
  const float* g2_lb  = (const float*)d_in[16];
  const float* g2_rW  = (const float*)d_in[17];
  const float* g2_rb  = (const float*)d_in[18];
  const float* g2_cW  = (const float*)d_in[19];
  const float* g2_cb  = (const float*)d_in[20];
  float* out  = (float*)d_out;
  float* ws   = (float*)d_ws;
  int*   wsI  = (int*)d_ws;
  float* bsum = ws + 16;
  float* H    = ws + H_OFF;            // TA in-place; HU2 = H + NM*DD
  float* TA2  = ws + TA2_OFF;
  float* rT   = ws + RT_OFF;
  float* qT   = ws + QT_OFF;
  float* lgp  = ws + LG_OFF;

  hipMemsetAsync(d_out, 0, (size_t)NB*NN*sizeof(float), stream);
  k_init<<<1, 64, 0, stream>>>(wsI, bsum);
  k_limits<<<(NE + 255)/256, 256, 0, stream>>>(edges, wsI);
  k_tables<<<NR + NB, 64, 0, stream>>>(rtab, qh, qr, pW, pb,
                                       g1_lW, g1_lb, g1_rW, g1_rb,
                                       g2_lW, g2_lb, g2_rW, g2_rb, rT, qT);
  k_proj<<<768, 256, 0, stream>>>(hcon, huncon, pW, pb, wsI, H);
  k_tf<<<PA + PB + PC, 256, 0, stream>>>(g1_lW, g1_rW, g2_lW, g2_rW, wsI, H, TA2);
  k_edges<<<512, 256, 0, stream>>>(edges, H, TA2, H + NM*DD, rT, qT,
                                   g1_cW, g1_cb, g2_cW, g2_cb, lgp);
  k_softmax<<<(NE + 255)/256, 256, 0, stream>>>(edges, lgp, na, out);
  k_rowsum<<<dim3(32, 16), 256, 0, stream>>>(out, bsum);
  k_div<<<(NB*NN + 255)/256, 256, 0, stream>>>(out, bsum);
}

// Round 5
// 817.636 us; speedup vs baseline: 1.0523x; 1.0523x over previous
//
#include <hip/hip_runtime.h>

#define DIN 100
#define DD  64
#define NE  250000
#define NB  16
#define NN  50000
#define NR  500
#define NM  500000
#define NH  (NM + NN)

// workspace layout (float offsets). H holds TA rows [0,nmax) and HU2 at rows >= NM.
#define H_OFF    64
#define TA2_OFF  (H_OFF + NH*DD)
#define RT_OFF   (TA2_OFF + NE*DD)
#define QT_OFF   (RT_OFF + 4*NR*DD)
#define LG_OFF   (QT_OFF + 4*NB*DD)

// k_projtf grid segmentation by work weight (proj K=100 + n_tf*64):
// pool0 ~1678 tiles * 228, pool1 ~1675 * 164, pool2 391 * 164
#define PA 408
#define PB 292
#define PC 68

#define US 132   // LDS tile stride (words); reads are 8-address broadcast, conflict-free

__device__ __forceinline__ void fma4x4(const float4 x, const float4 w, float4 acc[4]) {
  acc[0].x += x.x*w.x; acc[0].y += x.x*w.y; acc[0].z += x.x*w.z; acc[0].w += x.x*w.w;
  acc[1].x += x.y*w.x; acc[1].y += x.y*w.y; acc[1].z += x.y*w.z; acc[1].w += x.y*w.w;
  acc[2].x += x.z*w.x; acc[2].y += x.z*w.y; acc[2].z += x.z*w.z; acc[2].w += x.z*w.w;
  acc[3].x += x.w*w.x; acc[3].y += x.w*w.y; acc[3].z += x.w*w.z; acc[3].w += x.w*w.w;
}

__device__ __forceinline__ float fc(const float4& v, int i) {
  return ((const float*)&v)[i];
}

__device__ __forceinline__ float4 leaky4(float4 v) {
  v.x = v.x > 0.f ? v.x : 0.2f*v.x;
  v.y = v.y > 0.f ? v.y : 0.2f*v.y;
  v.z = v.z > 0.f ? v.z : 0.2f*v.z;
  v.w = v.w > 0.f ? v.w : 0.2f*v.w;
  return v;
}

__global__ void k_init(int* wsI, float* bsum) {
  if (threadIdx.x == 0) { wsI[0] = 0x7fffffff; wsI[1] = 0; }
  if (threadIdx.x < NB) bsum[threadIdx.x] = 0.f;
}

__global__ void k_limits(const int* __restrict__ edges, int* __restrict__ wsI) {
  int i = blockIdx.x * blockDim.x + threadIdx.x;
  int mn = 0x7fffffff, mx = -1;
  if (i < NE) { int v = edges[i*8 + 7]; mn = v; mx = v; }
  for (int off = 32; off > 0; off >>= 1) {
    mn = min(mn, __shfl_down(mn, off));
    mx = max(mx, __shfl_down(mx, off));
  }
  if ((threadIdx.x & 63) == 0) {
    atomicMin(&wsI[0], mn);
    atomicMax(&wsI[1], mx + 1);
  }
}

// one 64-thread block per (rel row | batch row): builds per-rel / per-batch tables
__global__ void k_tables(const float* __restrict__ rtab,
                         const float* __restrict__ qh, const float* __restrict__ qr,
                         const float* __restrict__ pW, const float* __restrict__ pb,
                         const float* __restrict__ g1_lW, const float* __restrict__ g1_lb,
                         const float* __restrict__ g1_rW, const float* __restrict__ g1_rb,
                         const float* __restrict__ g2_lW, const float* __restrict__ g2_lb,
                         const float* __restrict__ g2_rW, const float* __restrict__ g2_rb,
                         float* __restrict__ rT, float* __restrict__ qT) {
  __shared__ float xs[DIN], xs2[DIN], ps[DD], ps2[DD];
  const int d = threadIdx.x;
  const int blk = blockIdx.x;
  if (blk < NR) {
    for (int k = d; k < DIN; k += 64) xs[k] = rtab[blk*DIN + k];
    __syncthreads();
    float a = pb[d];
    for (int k = 0; k < DIN; ++k) a += xs[k] * pW[k*DD + d];
    ps[d] = tanhf(a);
    __syncthreads();
    float o1 = 0.f, o2 = 0.f, o3 = 0.f, o4 = 0.f;
    for (int k = 0; k < DD; ++k) {
      float p = ps[k];
      o1 += p * g1_lW[(DD + k)*DD + d];
      o2 += p * g1_rW[(DD + k)*DD + d];
      o3 += p * g2_lW[(DD + k)*DD + d];
      o4 += p * g2_rW[(DD + k)*DD + d];
    }
    rT[(0*NR + blk)*DD + d] = o1;
    rT[(1*NR + blk)*DD + d] = o2;
    rT[(2*NR + blk)*DD + d] = o3;
    rT[(3*NR + blk)*DD + d] = o4;
  } else {
    const int b = blk - NR;
    for (int k = d; k < DIN; k += 64) { xs[k] = qh[b*DIN + k]; xs2[k] = qr[b*DIN + k]; }
    __syncthreads();
    float a = pb[d], a2 = pb[d];
    for (int k = 0; k < DIN; ++k) { a += xs[k]*pW[k*DD + d]; a2 += xs2[k]*pW[k*DD + d]; }
    ps[d] = tanhf(a); ps2[d] = tanhf(a2);
    __syncthreads();
    float o1 = g1_lb[d], o2 = g1_rb[d], o3 = g2_lb[d], o4 = g2_rb[d];
    for (int k = 0; k < DD; ++k) {
      float p = ps[k], p2 = ps2[k];
      o1 += p * g1_lW[(2*DD + k)*DD + d] + p2 * g1_lW[(3*DD + k)*DD + d];
      o2 += p * g1_rW[(2*DD + k)*DD + d] + p2 * g1_rW[(3*DD + k)*DD + d];
      o3 += p * g2_lW[(2*DD + k)*DD + d] + p2 * g2_lW[(3*DD + k)*DD + d];
      o4 += p * g2_rW[(2*DD + k)*DD + d] + p2 * g2_rW[(3*DD + k)*DD + d];
    }
    qT[(0*NB + b)*DD + d] = o1;
    qT[(1*NB + b)*DD + d] = o2;
    qT[(2*NB + b)*DD + d] = o3;
    qT[(3*NB + b)*DD + d] = o4;
  }
}

// Fused proj + transform. 128-row tiles, 256 threads, 4x8 register tile.
// X staged in LDS (streamed data); ALL weights read from global (small
// working set, L1/L2-resident, lane-group broadcast).
// pool0 rows<nvi:        TA = tanh(X@pW+pb)@g1_lW, TA2 = .@g2_lW
// pool1 rows [nvi,nmax): TA = .@g1_rW
// pool2 huncon:          HU2 = .@g2_rW   (HU2 = H + NM*DD)
__global__ __launch_bounds__(256, 3)
void k_projtf(const float* __restrict__ hcon, const float* __restrict__ huncon,
              const float* __restrict__ pW, const float* __restrict__ pb,
              const float* __restrict__ g1_lW, const float* __restrict__ g1_rW,
              const float* __restrict__ g2_lW, const float* __restrict__ g2_rW,
              const int* __restrict__ lim,
              float* __restrict__ H, float* __restrict__ TA2) {
  __shared__ __align__(16) float U[DIN*US];   // 52.8 KB: Xt[100][132] then Ht[64][132]
  const int tid = threadIdx.x;
  const int nvi  = lim[0];
  const int nmax = lim[1];
  int pool, pbase, pgrid;
  if (blockIdx.x < PA)           { pool = 0; pbase = blockIdx.x;           pgrid = PA; }
  else if (blockIdx.x < PA + PB) { pool = 1; pbase = blockIdx.x - PA;      pgrid = PB; }
  else                           { pool = 2; pbase = blockIdx.x - PA - PB; pgrid = PC; }
  int t_begin, t_count, row_base, rlim, wlo, whi;
  const float* Xsrc;
  const float* W0;          // -> TA (or HU2)
  const float* W1 = nullptr; // -> TA2 (pool0 only)
  if (pool == 0) {
    t_begin = 0; t_count = (nvi + 127) >> 7; row_base = 0; rlim = nmax;
    wlo = 0; whi = nvi; Xsrc = hcon; W0 = g1_lW; W1 = g2_lW;
  } else if (pool == 1) {
    t_begin = nvi >> 7; t_count = ((nmax + 127) >> 7) - (nvi >> 7); row_base = 0; rlim = nmax;
    wlo = nvi; whi = nmax; Xsrc = hcon; W0 = g1_rW;
  } else {
    t_begin = 0; t_count = (NN + 127) >> 7; row_base = NM; rlim = NH;
    wlo = NM; whi = NH; Xsrc = huncon; W0 = g2_rW;
  }
  const int tc = tid & 7, tr = tid >> 3;      // 32 row-groups x 8 col-groups
  const int c0 = tc << 3;                     // cols c0..c0+7
  const int r0 = tr << 2;                     // rows r0..r0+3 (within tile)
  const float4 pb0 = *(const float4*)&pb[c0];
  const float4 pb1 = *(const float4*)&pb[c0 + 4];
  const int srow = tid >> 1;                  // staging: 2 threads per row
  const int kbeg = (tid & 1) ? 48 : 0;
  const int kcnt = (tid & 1) ? 52 : 48;

  for (int tt = pbase; tt < t_count; tt += pgrid) {
    const int row0 = row_base + ((t_begin + tt) << 7);
    // ---- stage X tile (LDS [k][row]) ----
    {
      int row = row0 + srow;
      if (row >= rlim) row = rlim - 1;
      const float* src = Xsrc + (size_t)(row - row_base)*DIN + kbeg;
      #pragma unroll
      for (int j = 0; j < 52; j += 4) {
        if (j < kcnt) {
          float4 v = *(const float4*)(src + j);
          U[(kbeg+j+0)*US + srow] = v.x;
          U[(kbeg+j+1)*US + srow] = v.y;
          U[(kbeg+j+2)*US + srow] = v.z;
          U[(kbeg+j+3)*US + srow] = v.w;
        }
      }
    }
    __syncthreads();
    // ---- proj: H = tanh(X @ pW + pb), acc 4 rows x 8 cols ----
    float4 ap0[4] = {{0,0,0,0},{0,0,0,0},{0,0,0,0},{0,0,0,0}};
    float4 ap1[4] = {{0,0,0,0},{0,0,0,0},{0,0,0,0},{0,0,0,0}};
    #pragma unroll 4
    for (int k = 0; k < DIN; ++k) {
      float4 x  = *(const float4*)&U[k*US + r0];
      float4 w0 = *(const float4*)&pW[k*DD + c0];
      float4 w1 = *(const float4*)&pW[k*DD + c0 + 4];
      fma4x4(x, w0, ap0);
      fma4x4(x, w1, ap1);
    }
    __syncthreads();   // all Xt reads complete before Ht overwrite
    // ---- handoff: Ht[col][row] = tanh(acc + pb) ----
    #pragma unroll
    for (int c = 0; c < 4; ++c) {
      float4 hv;
      hv.x = tanhf(fc(ap0[0], c) + fc(pb0, c));
      hv.y = tanhf(fc(ap0[1], c) + fc(pb0, c));
      hv.z = tanhf(fc(ap0[2], c) + fc(pb0, c));
      hv.w = tanhf(fc(ap0[3], c) + fc(pb0, c));
      *(float4*)&U[(c0 + c)*US + r0] = hv;
    }
    #pragma unroll
    for (int c = 0; c < 4; ++c) {
      float4 hv;
      hv.x = tanhf(fc(ap1[0], c) + fc(pb1, c));
      hv.y = tanhf(fc(ap1[1], c) + fc(pb1, c));
      hv.z = tanhf(fc(ap1[2], c) + fc(pb1, c));
      hv.w = tanhf(fc(ap1[3], c) + fc(pb1, c));
      *(float4*)&U[(c0 + 4 + c)*US + r0] = hv;
    }
    __syncthreads();
    // ---- transform(s): out = Ht^T @ W, weights from global ----
    if (pool == 0) {
      float4 t0a[4] = {{0,0,0,0},{0,0,0,0},{0,0,0,0},{0,0,0,0}};
      float4 t0b[4] = {{0,0,0,0},{0,0,0,0},{0,0,0,0},{0,0,0,0}};
      float4 t1a[4] = {{0,0,0,0},{0,0,0,0},{0,0,0,0},{0,0,0,0}};
      float4 t1b[4] = {{0,0,0,0},{0,0,0,0},{0,0,0,0},{0,0,0,0}};
      #pragma unroll 4
      for (int k = 0; k < DD; ++k) {
        float4 x  = *(const float4*)&U[k*US + r0];
        float4 w0 = *(const float4*)&W0[k*DD + c0];
        float4 w1 = *(const float4*)&W0[k*DD + c0 + 4];
        float4 u0 = *(const float4*)&W1[k*DD + c0];
        float4 u1 = *(const float4*)&W1[k*DD + c0 + 4];
        fma4x4(x, w0, t0a); fma4x4(x, w1, t0b);
        fma4x4(x, u0, t1a); fma4x4(x, u1, t1b);
      }
      #pragma unroll
      for (int r = 0; r < 4; ++r) {
        int row = row0 + r0 + r;
        if (row >= wlo && row < whi) {
          *(float4*)&H[(size_t)row*DD + c0]       = t0a[r];
          *(float4*)&H[(size_t)row*DD + c0 + 4]   = t0b[r];
          *(float4*)&TA2[(size_t)row*DD + c0]     = t1a[r];
          *(float4*)&TA2[(size_t)row*DD + c0 + 4] = t1b[r];
        }
      }
    } else {
      float4 t0a[4] = {{0,0,0,0},{0,0,0,0},{0,0,0,0},{0,0,0,0}};
      float4 t0b[4] = {{0,0,0,0},{0,0,0,0},{0,0,0,0},{0,0,0,0}};
      #pragma unroll 4
      for (int k = 0; k < DD; ++k) {
        float4 x  = *(const float4*)&U[k*US + r0];
        float4 w0 = *(const float4*)&W0[k*DD + c0];
        float4 w1 = *(const float4*)&W0[k*DD + c0 + 4];
        fma4x4(x, w0, t0a); fma4x4(x, w1, t0b);
      }
      #pragma unroll
      for (int r = 0; r < 4; ++r) {
        int row = row0 + r0 + r;
        if (row >= wlo && row < whi) {
          *(float4*)&H[(size_t)row*DD + c0]     = t0a[r];
          *(float4*)&H[(size_t)row*DD + c0 + 4] = t0b[r];
        }
      }
    }
    __syncthreads();   // Ht reads complete before next tile's staging
  }
}

// persistent edge kernel: cW1/cW2 transposed + cb resident in LDS.
// Dot partials reduced via wave-local __shfl_xor (edge-quad owned by 16
// consecutive lanes) instead of LDS atomics.
__global__ __launch_bounds__(256, 2)
void k_edges(const int* __restrict__ edges,
             const float* __restrict__ TA, const float* __restrict__ TA2,
             const float* __restrict__ HU2,
             const float* __restrict__ rT, const float* __restrict__ qT,
             const float* __restrict__ cW1, const float* __restrict__ cb1,
             const float* __restrict__ cW2, const float* __restrict__ cb2,
             float* __restrict__ logits) {
  __shared__ __align__(16) float Wt1s[DD*68];
  __shared__ __align__(16) float Wt2s[DD*68];
  __shared__ __align__(16) float Lt[DD][68];
  __shared__ __align__(16) float Rt[DD][68];
  __shared__ __align__(16) float4 cbs4[2][16];
  __shared__ float lg[64];
  __shared__ int   se[64*8];
  const int tid = threadIdx.x;
  for (int i = tid; i < DD*DD; i += 256) {
    int k = i >> 6, d = i & 63;
    Wt1s[d*68 + k] = cW1[i];   // Wt[d][k] = cW[k][d]
    Wt2s[d*68 + k] = cW2[i];
  }
  if (tid < 16) {
    cbs4[0][tid] = *(const float4*)&cb1[tid*4];
    cbs4[1][tid] = *(const float4*)&cb2[tid*4];
  }
  const int e   = tid >> 2;          // staging: 4 lanes per edge
  const int d0  = (tid & 3) * 16;
  const int eq0 = (tid >> 4) << 2;   // GEMM/dot: edge-quad (wave-local owners)
  const int jq0 = (tid & 15) << 2;   // j-quad
  __syncthreads();
  const int NT = (NE + 63) / 64;
  for (int tile = blockIdx.x; tile < NT; tile += gridDim.x) {
    const int e0 = tile * 64;
    const int ecnt = min(64, NE - e0);
    for (int i = tid; i < 64*8; i += 256) se[i] = (i < ecnt*8) ? edges[e0*8 + i] : 0;
    if (tid < 64) lg[tid] = 0.f;
    __syncthreads();
    const int rel = se[e*8 + 3];
    const int eg  = se[e*8 + 0];
    const int li  = se[e*8 + 6];
    for (int g = 0; g < 2; ++g) {
      const float* Lb = g ? TA2 : TA;
      const float* Rb = g ? HU2 : TA;
      const float* rL = rT + (g ? 2*NR*DD : 0);
      const float* rR = rT + (g ? 3*NR*DD : 1*NR*DD);
      const float* qL = qT + (g ? 2*NB*DD : 0);
      const float* qR = qT + (g ? 3*NB*DD : 1*NB*DD);
      const float* Wts = g ? Wt2s : Wt1s;
      const int ri = g ? se[e*8 + 2] : se[e*8 + 7];
      float cbp = 0.f;
      #pragma unroll
      for (int di = 0; di < 4; ++di) {
        const int d = d0 + 4*di;
        float4 l = *(const float4*)&Lb[(size_t)li*DD + d];
        float4 t = *(const float4*)&rL[rel*DD + d];
        float4 u = *(const float4*)&qL[eg*DD + d];
        l.x += t.x + u.x; l.y += t.y + u.y; l.z += t.z + u.z; l.w += t.w + u.w;
        l = leaky4(l);
        Lt[d+0][e] = l.x; Lt[d+1][e] = l.y; Lt[d+2][e] = l.z; Lt[d+3][e] = l.w;
        float4 c = cbs4[g][d >> 2];
        cbp += l.x*c.x + l.y*c.y + l.z*c.z + l.w*c.w;
        float4 r = *(const float4*)&Rb[(size_t)ri*DD + d];
        t = *(const float4*)&rR[rel*DD + d];
        u = *(const float4*)&qR[eg*DD + d];
        r.x += t.x + u.x; r.y += t.y + u.y; r.z += t.z + u.z; r.w += t.w + u.w;
        r = leaky4(r);
        Rt[d+0][e] = r.x; Rt[d+1][e] = r.y; Rt[d+2][e] = r.z; Rt[d+3][e] = r.w;
      }
      atomicAdd(&lg[e], cbp);
      __syncthreads();
      float4 z[4] = {{0,0,0,0},{0,0,0,0},{0,0,0,0},{0,0,0,0}};
      for (int d = 0; d < DD; ++d) {
        float4 x = *(const float4*)&Lt[d][eq0];        // broadcast across 16 lanes
        float4 w = *(const float4*)&Wts[d*68 + jq0];
        fma4x4(x, w, z);  // z[edge in quad][j in quad]
      }
      float4 rv0 = *(const float4*)&Rt[jq0+0][eq0];
      float4 rv1 = *(const float4*)&Rt[jq0+1][eq0];
      float4 rv2 = *(const float4*)&Rt[jq0+2][eq0];
      float4 rv3 = *(const float4*)&Rt[jq0+3][eq0];
      float p0 = z[0].x*rv0.x + z[0].y*rv1.x + z[0].z*rv2.x + z[0].w*rv3.x;
      float p1 = z[1].x*rv0.y + z[1].y*rv1.y + z[1].z*rv2.y + z[1].w*rv3.y;
      float p2 = z[2].x*rv0.z + z[2].y*rv1.z + z[2].z*rv2.z + z[2].w*rv3.z;
      float p3 = z[3].x*rv0.w + z[3].y*rv1.w + z[3].z*rv2.w + z[3].w*rv3.w;
      #pragma unroll
      for (int m = 1; m < 16; m <<= 1) {
        p0 += __shfl_xor(p0, m);
        p1 += __shfl_xor(p1, m);
        p2 += __shfl_xor(p2, m);
        p3 += __shfl_xor(p3, m);
      }
      if ((tid & 15) == 0) {   // unique owner per edge; cbp atomics drained by barrier
        lg[eq0+0] += p0;
        lg[eq0+1] += p1;
        lg[eq0+2] += p2;
        lg[eq0+3] += p3;
      }
      __syncthreads();
    }
    if (tid < ecnt) logits[e0 + tid] = lg[tid];
    __syncthreads();
  }
}

__global__ void k_softmax(const int* __restrict__ edges, const float* __restrict__ logits,
                          const float* __restrict__ na, float* __restrict__ out) {
  int e = blockIdx.x * blockDim.x + threadIdx.x;
  if (e >= NE) return;
  int seg = edges[e*8 + 4];
  if (e > 0 && edges[(e-1)*8 + 4] == seg) return;  // not a segment head
  int j = e;
  float m = -1e30f;
  while (j < NE && edges[j*8 + 4] == seg) { m = fmaxf(m, logits[j]); ++j; }
  float s = 0.f;
  for (int t = e; t < j; ++t) s += expf(logits[t] - m);
  int eg = edges[e*8 + 0], vi = edges[e*8 + 1];
  float scale = na[eg*NN + vi] / s;
  for (int t = e; t < j; ++t) {
    int vj = edges[t*8 + 2];
    __hip_atomic_fetch_add(&out[eg*NN + vj], expf(logits[t] - m) * scale,
                           __ATOMIC_RELAXED, __HIP_MEMORY_SCOPE_AGENT);
  }
}

__global__ void k_rowsum(const float* __restrict__ out, float* __restrict__ bsum) {
  int b = blockIdx.y;
  float s = 0.f;
  for (int n = blockIdx.x * blockDim.x + threadIdx.x; n < NN; n += gridDim.x * blockDim.x)
    s += out[b*NN + n];
  for (int off = 32; off > 0; off >>= 1) s += __shfl_down(s, off);
  if ((threadIdx.x & 63) == 0)
    __hip_atomic_fetch_add(&bsum[b], s, __ATOMIC_RELAXED, __HIP_MEMORY_SCOPE_AGENT);
}

__global__ void k_div(float* __restrict__ out, const float* __restrict__ bsum) {
  int i = blockIdx.x * blockDim.x + threadIdx.x;
  if (i < NB*NN) out[i] /= bsum[i / NN];
}

extern "C" void kernel_launch(void* const* d_in, const int* in_sizes, int n_in,
                              void* d_out, int out_size, void* d_ws, size_t ws_size,
                              hipStream_t stream) {
  (void)in_sizes; (void)n_in; (void)out_size; (void)ws_size;
  const float* na     = (const float*)d_in[0];
  const int*   edges  = (const int*)  d_in[1];
  const float* huncon = (const float*)d_in[2];
  const float* hcon   = (const float*)d_in[3];
  const float* rtab   = (const float*)d_in[4];
  const float* qh     = (const float*)d_in[5];
  const float* qr     = (const float*)d_in[6];
  const float* pW     = (const float*)d_in[7];
  const float* pb     = (const float*)d_in[8];
  const float* g1_lW  = (const float*)d_in[9];
  const float* g1_lb  = (const float*)d_in[10];
  const float* g1_rW  = (const float*)d_in[11];
  const float* g1_rb  = (const float*)d_in[12];
  const float* g1_cW  = (const float*)d_in[13];
  const float* g1_cb  = (const float*)d_in[14];
  const float* g2_lW  = (const float*)d_in[15];
  const float* g2_lb  = (const float*)d_in[16];
  const float* g2_rW  = (const float*)d_in[17];
  const float* g2_rb  = (const float*)d_in[18];
  const float* g2_cW  = (const float*)d_in[19];
  const float* g2_cb  = (const float*)d_in[20];
  float* out  = (float*)d_out;
  float* ws   = (float*)d_ws;
  int*   wsI  = (int*)d_ws;
  float* bsum = ws + 16;
  float* H    = ws + H_OFF;            // TA rows [0,nmax); HU2 = H + NM*DD
  float* TA2  = ws + TA2_OFF;
  float* rT   = ws + RT_OFF;
  float* qT   = ws + QT_OFF;
  float* lgp  = ws + LG_OFF;

  hipMemsetAsync(d_out, 0, (size_t)NB*NN*sizeof(float), stream);
  k_init<<<1, 64, 0, stream>>>(wsI, bsum);
  k_limits<<<(NE + 255)/256, 256, 0, stream>>>(edges, wsI);
  k_tables<<<NR + NB, 64, 0, stream>>>(rtab, qh, qr, pW, pb,
                                       g1_lW, g1_lb, g1_rW, g1_rb,
                                       g2_lW, g2_lb, g2_rW, g2_rb, rT, qT);
  k_projtf<<<PA + PB + PC, 256, 0, stream>>>(hcon, huncon, pW, pb,
                                             g1_lW, g1_rW, g2_lW, g2_rW,
                                             wsI, H, TA2);
  k_edges<<<512, 256, 0, stream>>>(edges, H, TA2, H + NM*DD, rT, qT,
                                   g1_cW, g1_cb, g2_cW, g2_cb, lgp);
  k_softmax<<<(NE + 255)/256, 256, 0, stream>>>(edges, lgp, na, out);
  k_rowsum<<<dim3(32, 16), 256, 0, stream>>>(out, bsum);
  k_div<<<(NB*NN + 255)/256, 256, 0, stream>>>(out, bsum);
}